// Round 6
// baseline (362.144 us; speedup 1.0000x reference)
//
#include <hip/hip_runtime.h>

// Leaky LIF SNN forward, x/spk: [T=128, B*N=262144] fp32.
//   reset_t = H(mem_{t-1} - 1); mem_t = 0.5*mem_{t-1} + x_t - reset_t; spk_t = H(mem_t - 1)
//
// R9: NOT BW-bound: R0 (335MB logical) == R6 (268MB) == ~79us, and nt-store
// changed nothing (FETCH identical 65.6MB). Revised theory: with ~256B
// channel interleave, a DRAM row (~128KB of address space) gets reuse only
// if the blocks covering it arrive together; 2-4KB visits from 512 drifting
// streams never do -> row-activate bound ~2.3 TB/s on both streams.
// Axis that historically moved perf: visit size (256B scalar = 2.45 TB/s;
// 1-4KB = 79us plateau). Push to 8KB/block-row: G=2 float4 cols/thread,
// 256-thr blocks (the geometry that benched 79us, not R7b's 512-thr),
// 128 col-slabs x 4 T-phases = 512 blocks, 2/CU, 8 waves/CU.
// Warmup recompute is ~free (R0: +134MB logical reads cost 0 time; rows
// are L3-served). Phase in HIGH bits: all 4 phases of a slab share the
// XCD (blockIdx%8 = slab%8), like R0. Plain stores (nt regressed, R7b).

#define T_STEPS 128
#define P 4
#define TP (T_STEPS / P)   // 32 rows stored per phase
#define D 8                // rolling ring depth (rows in flight per thread)
#define BLKT 256
#define G 2                // float4 columns per thread -> 8KB chunk per block-row

__device__ __forceinline__ float4 lif_step(float4& mem, const float4 v) {
    // RHS uses OLD mem (reset term is H(mem_{t-1} - 1))
    mem.x = 0.5f * mem.x + v.x - (mem.x > 1.0f ? 1.0f : 0.0f);
    mem.y = 0.5f * mem.y + v.y - (mem.y > 1.0f ? 1.0f : 0.0f);
    mem.z = 0.5f * mem.z + v.z - (mem.z > 1.0f ? 1.0f : 0.0f);
    mem.w = 0.5f * mem.w + v.w - (mem.w > 1.0f ? 1.0f : 0.0f);
    float4 s;
    s.x = mem.x > 1.0f ? 1.0f : 0.0f;
    s.y = mem.y > 1.0f ? 1.0f : 0.0f;
    s.z = mem.z > 1.0f ? 1.0f : 0.0f;
    s.w = mem.w > 1.0f ? 1.0f : 0.0f;
    return s;
}

__global__ __launch_bounds__(BLKT) void snn_leaky_fwd(const float4* __restrict__ x,
                                                      float4* __restrict__ out,
                                                      int n4) {
    const int slab  = blockIdx.x & 127;   // 128 column slabs of 8KB
    const int phase = blockIdx.x >> 7;    // 4 phases; blockIdx%8 == slab%8 -> same XCD
    const int col0  = slab * (BLKT * G) + threadIdx.x;
    const float4* xp = x + col0;
    float4* op = out + col0;
    const int t_beg = phase * TP;
    const int t_end = t_beg + TP;

    float4 buf[D][G];
    float4 mem[G];
#pragma unroll
    for (int g = 0; g < G; ++g) mem[g] = make_float4(0.f, 0.f, 0.f, 0.f);

    // prime ring with rows 0..D-1 (D=8 <= 32 = first phase length, always valid)
#pragma unroll
    for (int u = 0; u < D; ++u)
#pragma unroll
        for (int g = 0; g < G; ++g)
            buf[u][g] = xp[(size_t)u * n4 + g * BLKT];

    // warmup rows [0, t_beg): bit-identical mem recurrence, no stores.
    // (t+D <= t_beg+7 < t_end always, so prefetch is unconditional here)
    for (int t = 0; t < t_beg; ++t) {
#pragma unroll
        for (int g = 0; g < G; ++g) {
            const float4 v = buf[t & (D - 1)][g];
            buf[t & (D - 1)][g] = xp[(size_t)(t + D) * n4 + g * BLKT];
            (void)lif_step(mem[g], v);   // updates mem[g] by ref (live, not DCE'd)
        }
    }

    // compute + store rows [t_beg, t_end)
    for (int t = t_beg; t < t_end; ++t) {
#pragma unroll
        for (int g = 0; g < G; ++g) {
            const float4 v = buf[t & (D - 1)][g];
            if (t + D < t_end) buf[t & (D - 1)][g] = xp[(size_t)(t + D) * n4 + g * BLKT];
            const float4 s = lif_step(mem[g], v);
            op[(size_t)t * n4 + g * BLKT] = s;
        }
    }
}

extern "C" void kernel_launch(void* const* d_in, const int* in_sizes, int n_in,
                              void* d_out, int out_size, void* d_ws, size_t ws_size,
                              hipStream_t stream) {
    const float4* x = (const float4*)d_in[0];
    float4* out = (float4*)d_out;

    const int total = in_sizes[0];            // T*B*N = 128*64*4096
    const int n4 = total / T_STEPS / 4;       // 65536 float4 columns

    // 128 slabs x 4 phases = 512 blocks x 256 thr: 2 blocks/CU, 8 waves/CU,
    // 8KB contiguous visit per block-row, phases XCD-colocated with their slab.
    snn_leaky_fwd<<<512, BLKT, 0, stream>>>(x, out, n4);
}

// Round 7
// 235.333 us; speedup vs baseline: 1.5389x; 1.5389x over previous
//
#include <hip/hip_runtime.h>

// Leaky LIF SNN forward, x/spk: [T=128, B*N=262144] fp32.
//   reset_t = H(mem_{t-1} - 1); mem_t = 0.5*mem_{t-1} + x_t - reset_t; spk_t = H(mem_t - 1)
//
// R10 = R9's 8KB-visit hypothesis, re-run with R0's PROVEN STATIC structure.
// R9 post-mortem: runtime loop bound (t_beg) blocked unrolling -> buf[]
// runtime-indexed -> scratch spill (VGPR=36 < 64 needed; WRITE 457MB =
// 131 out + 326 scratch; kernel 210us). The visit-size axis was never
// tested. Here: compile-time phase split (if/else, all loops #pragma
// unroll with constant bounds), G=2 float4 cols/thread, 256-thr blocks.
// 128 col-slabs x 2 phases = 256 blocks, 1/CU, 8KB contiguous visit per
// block-row (vs 1-4KB in the 71us plateau configs). Phase in HIGH bit:
// partner blocks share XCD (b%8 equal) so phase-1 warmup reads hit lines
// phase-0 just pulled (R0 proved warmup ~free). In-flight unchanged:
// 65536 thr x D8 x G2 x 16B ~= 16.8MB. Plain stores (nt regressed R7b).

#define T_STEPS 128
#define T_HALF 64
#define D 8     // rolling ring depth (rows in flight per thread, per col)
#define BLKT 256
#define G 2     // float4 columns per thread -> 8KB visit per block-row

__device__ __forceinline__ float4 lif_step(float4& mem, const float4 v) {
    // RHS uses OLD mem (reset term is H(mem_{t-1} - 1))
    mem.x = 0.5f * mem.x + v.x - (mem.x > 1.0f ? 1.0f : 0.0f);
    mem.y = 0.5f * mem.y + v.y - (mem.y > 1.0f ? 1.0f : 0.0f);
    mem.z = 0.5f * mem.z + v.z - (mem.z > 1.0f ? 1.0f : 0.0f);
    mem.w = 0.5f * mem.w + v.w - (mem.w > 1.0f ? 1.0f : 0.0f);
    float4 s;
    s.x = mem.x > 1.0f ? 1.0f : 0.0f;
    s.y = mem.y > 1.0f ? 1.0f : 0.0f;
    s.z = mem.z > 1.0f ? 1.0f : 0.0f;
    s.w = mem.w > 1.0f ? 1.0f : 0.0f;
    return s;
}

__global__ __launch_bounds__(BLKT) void snn_leaky_fwd(const float4* __restrict__ x,
                                                      float4* __restrict__ out,
                                                      int n4) {
    const int slab  = blockIdx.x & 127;   // 128 column slabs of 8KB
    const int phase = blockIdx.x >> 7;    // 2 phases; partner shares XCD (b%8)
    const int col0  = slab * (BLKT * G) + threadIdx.x;
    const float4* xp = x + col0;
    float4* op = out + col0;

    float4 buf[D][G];
    float4 mem[G];
#pragma unroll
    for (int g = 0; g < G; ++g) mem[g] = make_float4(0.f, 0.f, 0.f, 0.f);

#pragma unroll
    for (int u = 0; u < D; ++u)
#pragma unroll
        for (int g = 0; g < G; ++g)
            buf[u][g] = xp[(size_t)u * n4 + g * BLKT];

    if (phase == 0) {
#pragma unroll
        for (int t = 0; t < T_HALF; ++t) {
#pragma unroll
            for (int g = 0; g < G; ++g) {
                const float4 v = buf[t & (D - 1)][g];
                if (t + D < T_HALF) buf[t & (D - 1)][g] = xp[(size_t)(t + D) * n4 + g * BLKT];
                const float4 s = lif_step(mem[g], v);
                op[(size_t)t * n4 + g * BLKT] = s;
            }
        }
    } else {
        // warmup rows [0, 64): bit-identical mem recurrence, no stores.
        // t+D <= 71 < 128 always -> unconditional prefetch.
#pragma unroll
        for (int t = 0; t < T_HALF; ++t) {
#pragma unroll
            for (int g = 0; g < G; ++g) {
                const float4 v = buf[t & (D - 1)][g];
                buf[t & (D - 1)][g] = xp[(size_t)(t + D) * n4 + g * BLKT];
                (void)lif_step(mem[g], v);   // updates mem[g] by ref
            }
        }
#pragma unroll
        for (int t = T_HALF; t < T_STEPS; ++t) {
#pragma unroll
            for (int g = 0; g < G; ++g) {
                const float4 v = buf[t & (D - 1)][g];
                if (t + D < T_STEPS) buf[t & (D - 1)][g] = xp[(size_t)(t + D) * n4 + g * BLKT];
                const float4 s = lif_step(mem[g], v);
                op[(size_t)t * n4 + g * BLKT] = s;
            }
        }
    }
}

extern "C" void kernel_launch(void* const* d_in, const int* in_sizes, int n_in,
                              void* d_out, int out_size, void* d_ws, size_t ws_size,
                              hipStream_t stream) {
    const float4* x = (const float4*)d_in[0];
    float4* out = (float4*)d_out;

    const int total = in_sizes[0];            // T*B*N = 128*64*4096
    const int n4 = total / T_STEPS / 4;       // 65536 float4 columns

    // 128 slabs x 2 phases = 256 blocks x 256 thr: 1 block/CU, 4 waves/CU,
    // 8KB contiguous visit per block-row, phases XCD-colocated per slab.
    snn_leaky_fwd<<<256, BLKT, 0, stream>>>(x, out, n4);
}

// Round 8
// 232.989 us; speedup vs baseline: 1.5543x; 1.0101x over previous
//
#include <hip/hip_runtime.h>

// Leaky LIF SNN forward, x/spk: [T=128, B*N=262144] fp32.
//   reset_t = H(mem_{t-1} - 1); mem_t = 0.5*mem_{t-1} + x_t - reset_t; spk_t = H(mem_t - 1)
//
// R11: CHANNEL-CLUSTERED column ownership. Evidence: ~2.5 TB/s plateau is
// invariant across visit size 256B..8KB and waves/CU 8..16 (R0/R6/R7b/R10 +
// prev session); coherence-by-sync failed (R5). Diagnosis: with ~256B
// channel interleave over ~256 pseudo-channels (64KB superstripe), ANY
// device-contiguous visit <=8KB gives each channel exactly ONE 256B burst
// per page -> activate-bound, and a second hit would require drifting
// blocks to co-arrive in the same 256KB window (never happens).
// Fix: block g owns, per row, the 16 chunks at device addr g*256B + k*64KB
// (k=0..15) -> all in channel g, at CONSECUTIVE 256B slots of its local
// address space: dense sequential 4KB per row per channel, and row t+1
// (1MB device stride = 4KB channel-local stride) continues the run.
// Each channel served by ONE block (+ phase partner) -> page locality is
// DRIFT-IMMUNE, per-channel stream looks like memset/copy (6.3+ TB/s).
// float4 col = (tid>>4)*4096 + g*16 + (tid&15): 16-lane groups read
// contiguous 256B segments (4 txns/wave, fully coalesced at 64B lines).
// Skeleton = R0 verbatim: 2 T-phases (warmup recompute, proven ~free),
// 512 blocks x 256 thr = 8 waves/CU, D=8 ring, phase in HIGH bit so both
// phases of g share an XCD (b%8 equal) and phase-1 warmup reads hit L2/L3
// lines phase-0 pulled. Plain stores (nt regressed, R7b).

#define T_STEPS 128
#define T_HALF 64
#define D 8   // rolling ring depth (float4 rows in flight per thread: 8 KB/wave)

__device__ __forceinline__ float4 lif_step(float4& mem, const float4 v) {
    // RHS uses OLD mem (reset term is H(mem_{t-1} - 1))
    mem.x = 0.5f * mem.x + v.x - (mem.x > 1.0f ? 1.0f : 0.0f);
    mem.y = 0.5f * mem.y + v.y - (mem.y > 1.0f ? 1.0f : 0.0f);
    mem.z = 0.5f * mem.z + v.z - (mem.z > 1.0f ? 1.0f : 0.0f);
    mem.w = 0.5f * mem.w + v.w - (mem.w > 1.0f ? 1.0f : 0.0f);
    float4 s;
    s.x = mem.x > 1.0f ? 1.0f : 0.0f;
    s.y = mem.y > 1.0f ? 1.0f : 0.0f;
    s.z = mem.z > 1.0f ? 1.0f : 0.0f;
    s.w = mem.w > 1.0f ? 1.0f : 0.0f;
    return s;
}

__global__ __launch_bounds__(256) void snn_leaky_fwd(const float4* __restrict__ x,
                                                     float4* __restrict__ out,
                                                     int n4) {
    const int g     = blockIdx.x & 255;   // channel group (one per block pair)
    const int phase = blockIdx.x >> 8;    // 2 phases; b%8 equal -> same XCD
    const int tid   = threadIdx.x;
    // channel-clustered column: byte addr = (tid&15)*16 + g*256 + (tid>>4)*65536
    // -> 16 chunks of 256B per block-row, all mapping to channel g under a
    // 256B/256-channel round-robin interleave; channel-local stride 256B.
    const int col = ((tid >> 4) << 12) + (g << 4) + (tid & 15);

    const float4* xp = x + col;
    float4* op = out + col;

    float4 buf[D];
    float4 mem = make_float4(0.f, 0.f, 0.f, 0.f);

#pragma unroll
    for (int u = 0; u < D; ++u) buf[u] = xp[(size_t)u * n4];

    if (phase == 0) {
#pragma unroll
        for (int t = 0; t < T_HALF; ++t) {
            const float4 v = buf[t & (D - 1)];
            if (t + D < T_HALF) buf[t & (D - 1)] = xp[(size_t)(t + D) * n4];
            const float4 s = lif_step(mem, v);
            op[(size_t)t * n4] = s;
        }
    } else {
        // warmup: bit-identical mem recurrence for t in [0,64), no stores
#pragma unroll
        for (int t = 0; t < T_HALF; ++t) {
            const float4 v = buf[t & (D - 1)];
            buf[t & (D - 1)] = xp[(size_t)(t + D) * n4];   // t+D < 128 always here
            (void)lif_step(mem, v);
        }
#pragma unroll
        for (int t = T_HALF; t < T_STEPS; ++t) {
            const float4 v = buf[t & (D - 1)];
            if (t + D < T_STEPS) buf[t & (D - 1)] = xp[(size_t)(t + D) * n4];
            const float4 s = lif_step(mem, v);
            op[(size_t)t * n4] = s;
        }
    }
}

extern "C" void kernel_launch(void* const* d_in, const int* in_sizes, int n_in,
                              void* d_out, int out_size, void* d_ws, size_t ws_size,
                              hipStream_t stream) {
    const float4* x = (const float4*)d_in[0];
    float4* out = (float4*)d_out;

    const int total = in_sizes[0];            // T*B*N = 128*64*4096
    const int n4 = total / T_STEPS / 4;       // 65536 float4 columns

    // 256 channel-groups x 2 phases = 512 blocks -> 2 blocks/CU, 8 waves/CU.
    snn_leaky_fwd<<<512, 256, 0, stream>>>(x, out, n4);
}

// Round 9
// 226.185 us; speedup vs baseline: 1.6011x; 1.0301x over previous
//
#include <hip/hip_runtime.h>

// Leaky LIF SNN forward, x/spk: [T=128, B*N=262144] fp32.
//   reset_t = H(mem_{t-1} - 1); mem_t = 0.5*mem_{t-1} + x_t - reset_t; spk_t = H(mem_t - 1)
//
// R12: DIRECTION-BATCHED windows. Plateau map: ~80us/201MB HBM = 2.5 TB/s
// invariant across visit size (256B..8KB), waves/CU (8..16), channel
// clustering (R11, mapping likely hashed -> untestable), nt-store, -20%
// traffic (R6). Linear copy = 6.3 TB/s, memset = 6.7 on same chip. The one
// untested shared feature: fine-grained load/store alternation per wave.
// Mechanisms: (1) gfx9 vmcnt retires IN ORDER -> each wait-for-load sits
// behind a just-issued strided store, serializing reads behind write
// drain; (2) every channel sees R/W/R/W at KB grain from 2048 waves ->
// constant bus turnaround. memset/linear-copy avoid both.
// Fix: keep R6 geometry exactly (single phase, one read + one write per
// element, float2/thread, 512 blk x 256 thr, 8 waves/CU) but process T in
// 8 windows of 16: compute 16 rows -> 16 loads back-to-back (8KB
// same-direction run per wave) -> 16 stores back-to-back. The wait before
// window w's compute only covers loads issued BEFORE window w-1's stores,
// so 16 trailing stores stay in flight across it. All loops statically
// unrolled; buf/spk fully register-resident (R9 scratch lesson).

#define T_STEPS 128
#define W 16                    // rows per window
#define NW (T_STEPS / W)        // 8 windows
#define BLKT 256

__device__ __forceinline__ float2 lif_step(float2& mem, const float2 v) {
    // RHS uses OLD mem (reset term is H(mem_{t-1} - 1))
    mem.x = 0.5f * mem.x + v.x - (mem.x > 1.0f ? 1.0f : 0.0f);
    mem.y = 0.5f * mem.y + v.y - (mem.y > 1.0f ? 1.0f : 0.0f);
    float2 s;
    s.x = mem.x > 1.0f ? 1.0f : 0.0f;
    s.y = mem.y > 1.0f ? 1.0f : 0.0f;
    return s;
}

__global__ __launch_bounds__(BLKT) void snn_leaky_fwd(const float2* __restrict__ x,
                                                      float2* __restrict__ out,
                                                      int n2) {
    const int col = blockIdx.x * BLKT + threadIdx.x;   // one float2 column/thread
    const float2* xp = x + col;
    float2* op = out + col;

    float2 buf[W];
    float2 spk[W];
    float2 mem = make_float2(0.f, 0.f);

    // prime window 0: 16 loads back-to-back
#pragma unroll
    for (int k = 0; k < W; ++k) buf[k] = xp[(size_t)k * n2];

#pragma unroll
    for (int w = 0; w < NW; ++w) {
        // consume window w (waits only on its own loads; stores from
        // window w-1 were issued AFTER those loads -> stay outstanding)
#pragma unroll
        for (int k = 0; k < W; ++k) spk[k] = lif_step(mem, buf[k]);

        // prefetch window w+1: 16 loads, one same-direction 8KB run/wave
        if (w + 1 < NW) {
#pragma unroll
            for (int k = 0; k < W; ++k)
                buf[k] = xp[(size_t)((w + 1) * W + k) * n2];
        }

        // store window w: 16 stores, one same-direction 8KB run/wave
#pragma unroll
        for (int k = 0; k < W; ++k)
            op[(size_t)(w * W + k) * n2] = spk[k];
    }
}

extern "C" void kernel_launch(void* const* d_in, const int* in_sizes, int n_in,
                              void* d_out, int out_size, void* d_ws, size_t ws_size,
                              hipStream_t stream) {
    const float2* x = (const float2*)d_in[0];
    float2* out = (float2*)d_out;

    const int total = in_sizes[0];            // T*B*N = 128*64*4096
    const int n2 = total / T_STEPS / 2;       // 131072 float2 columns

    // 512 blocks x 256 threads = 131072 threads = n2: every float2 column
    // owned by exactly one thread; 2 blocks/CU, 8 waves/CU, single phase.
    snn_leaky_fwd<<<n2 / BLKT, BLKT, 0, stream>>>(x, out, n2);
}